// Round 1
// 42.523 us; speedup vs baseline: 1.1928x; 1.1928x over previous
//
#include <hip/hip_runtime.h>

#define B_ 4096
#define C_ 128
#define EPS_ATT 1e-9f
#define EPS_BN 1e-5f
#define LOG2E 1.44269504088896f

using short8 = __attribute__((ext_vector_type(8))) short;
using f32x4 = __attribute__((ext_vector_type(4))) float;
using u32x2 = __attribute__((ext_vector_type(2))) unsigned int;

__device__ __forceinline__ unsigned short bf16b(float x) {
    __bf16 h = (__bf16)x;
    return __builtin_bit_cast(unsigned short, h);
}

// ---------------------------------------------------------------------------
// Kernel 0: transpose conv_w -> WT (WT[i][o] = W[o][i]) for coalesced matvec.
__global__ __launch_bounds__(256) void k_transpose(const float* __restrict__ W,
                                                   float* __restrict__ WT) {
    int j = blockIdx.x * 256 + threadIdx.x;
    if (j < C_ * C_) {
        int r = j >> 7;
        int col = j & (C_ - 1);
        WT[col * C_ + r] = W[j];
    }
}

// ---------------------------------------------------------------------------
// Kernel 1: one batch per block, 256 threads (4 waves).
// NEW vs previous round: P1 stages bf16 e into XOR-swizzled LDS (32KB); P2
// reads it back (transposed) instead of re-exponentiating -> trans work
// halves. Conv uses float4 WT loads (16 VMEM vs 64). Conv partials alias
// the dead e-buffer so LDS stays at 40448B -> 4 blocks/CU.
__global__ __launch_bounds__(256, 4) void k_batch(
    const float* __restrict__ x1, const float* __restrict__ x2,
    const float* __restrict__ x12, const float* __restrict__ WT,
    const float* __restrict__ fcw, const float* __restrict__ fcb,
    const float* __restrict__ convb,
    float* __restrict__ Y, float* __restrict__ GX1) {
    const int b = blockIdx.x;
    const int tid = threadIdx.x;
    const int lane = tid & 63;
    const int w = tid >> 6;     // wave 0..3
    const int g = lane >> 4;    // k-group 0..3
    const int ls = lane & 15;   // sixteen-index

    // 32KB: bf16 e[128][128] (swizzled rows) in P1/P2; conv partials after B5.
    __shared__ char s_buf[C_ * C_ * 2] __attribute__((aligned(16)));
    __shared__ float s_x1[C_] __attribute__((aligned(16)));
    __shared__ float s_x2[C_] __attribute__((aligned(16)));
    __shared__ float s_fcC[C_] __attribute__((aligned(16)));
    __shared__ float s_invZ[C_] __attribute__((aligned(16)));
    __shared__ float s_cs4[4][C_] __attribute__((aligned(16)));
    __shared__ float s_s24[4][C_] __attribute__((aligned(16)));
    __shared__ float s_S1[C_] __attribute__((aligned(16)));
    __shared__ float s_xr[C_] __attribute__((aligned(16)));
    __shared__ unsigned short s_w3bf[C_] __attribute__((aligned(16)));
    __shared__ unsigned short s_f1bf[C_] __attribute__((aligned(16)));

    // ---- preload (threads 0..127, coalesced). v12/vcb prefetched to regs.
    float v12 = 0.f, vcb = 0.f;
    if (tid < C_) {
        float v1 = x1[b * C_ + tid];
        s_x1[tid] = v1;
        s_x2[tid] = x2[b * C_ + tid];
        s_f1bf[tid] = bf16b(fcw[tid]);
        s_fcC[tid] = fcw[C_ + tid];
        v12 = x12[b * C_ + tid];
        vcb = convb[tid];
    }
    __syncthreads();  // B0

    // ---- P1: e-fragments in registers + bf16 e staged to swizzled LDS.
    // Row r cell c (16B = 8 cols) stored at byte r*256 + ((c ^ (r&7))<<4).
    short8 ef0[4], ef1[4];  // tiles m0=2w, m1=2w+1; chunks q=0..3
    float zp0 = 0.f, zp1 = 0.f;
    {
        const float r0 = s_x1[32 * w + ls] * LOG2E;
        const float r1 = s_x1[32 * w + 16 + ls] * LOG2E;
        char* erow0 = s_buf + (32 * w + ls) * 256;
        char* erow1 = s_buf + (32 * w + 16 + ls) * 256;
        const int sw = (ls & 7) << 4;  // same for both rows (differ by 16)
#pragma unroll
        for (int q = 0; q < 4; ++q) {
            f32x4 xa = *(const f32x4*)&s_x2[32 * q + 8 * g];      // broadcast
            f32x4 xb = *(const f32x4*)&s_x2[32 * q + 8 * g + 4];  // broadcast
            union {
                short8 v;
                unsigned short u[8];
            } p0, p1;
#pragma unroll
            for (int j = 0; j < 4; ++j) {
                float a0 = __builtin_amdgcn_exp2f(r0 * xa[j]);
                float b0 = __builtin_amdgcn_exp2f(r0 * xb[j]);
                float a1 = __builtin_amdgcn_exp2f(r1 * xa[j]);
                float b1 = __builtin_amdgcn_exp2f(r1 * xb[j]);
                zp0 += a0 + b0;
                zp1 += a1 + b1;
                p0.u[j] = bf16b(a0);
                p0.u[j + 4] = bf16b(b0);
                p1.u[j] = bf16b(a1);
                p1.u[j + 4] = bf16b(b1);
            }
            ef0[q] = p0.v;
            ef1[q] = p1.v;
            const int off = (64 * q + 16 * g) ^ sw;  // swizzled cell offset
            *(short8*)(erow0 + off) = p0.v;
            *(short8*)(erow1 + off) = p1.v;
        }
    }
    // butterfly over g-lanes (xor 16, then 32): every lane gets full row sums
    zp0 += __shfl_xor(zp0, 16);
    zp0 += __shfl_xor(zp0, 32);
    zp1 += __shfl_xor(zp1, 16);
    zp1 += __shfl_xor(zp1, 32);
    if (lane < 16) {
        s_invZ[32 * w + ls] = 1.f / zp0;
        s_invZ[32 * w + 16 + ls] = 1.f / zp1;
    }
    __syncthreads();  // B1

    // ---- P2: colsum/S2 from staged bf16 e (no exp recompute).
    // Thread: cols grp*4..+3, rows sl*16..+15. Wave holds slices {2w,2w+1};
    // one shfl_xor(32) merges them, leaders write the wave partial.
    {
        const int grp = tid & 31;
        const int sl = tid >> 5;
        const char* eb = s_buf + sl * 16 * 256;
        const int octb = grp >> 1;        // 16B cell index
        const int hoff = (grp & 1) * 8;   // half-cell byte offset
        float cs[4] = {0.f, 0.f, 0.f, 0.f};
        float s2[4] = {0.f, 0.f, 0.f, 0.f};
#pragma unroll
        for (int k = 0; k < 4; ++k) {
            f32x4 iz4 = *(const f32x4*)&s_invZ[sl * 16 + 4 * k];  // broadcast
            f32x4 fc4 = *(const f32x4*)&s_fcC[sl * 16 + 4 * k];   // broadcast
#pragma unroll
            for (int rr = 0; rr < 4; ++rr) {
                const int r = 4 * k + rr;
                const float iz = iz4[rr];
                const float izf = iz * fc4[rr];
                u32x2 ev = *(const u32x2*)(eb + r * 256 +
                                           ((octb ^ (r & 7)) << 4) + hoff);
#pragma unroll
                for (int d = 0; d < 2; ++d) {
                    float elo = __builtin_bit_cast(float, ev[d] << 16);
                    float ehi =
                        __builtin_bit_cast(float, ev[d] & 0xffff0000u);
                    cs[2 * d] = fmaf(elo, iz, cs[2 * d]);
                    s2[2 * d] = fmaf(elo, izf, s2[2 * d]);
                    cs[2 * d + 1] = fmaf(ehi, iz, cs[2 * d + 1]);
                    s2[2 * d + 1] = fmaf(ehi, izf, s2[2 * d + 1]);
                }
            }
        }
#pragma unroll
        for (int k = 0; k < 4; ++k) {
            cs[k] += __shfl_xor(cs[k], 32);
            s2[k] += __shfl_xor(s2[k], 32);
        }
        if ((sl & 1) == 0) {  // lanes 0..31 of each wave
            f32x4 c4 = {cs[0], cs[1], cs[2], cs[3]};
            f32x4 t4 = {s2[0], s2[1], s2[2], s2[3]};
            *(f32x4*)&s_cs4[w][grp * 4] = c4;
            *(f32x4*)&s_s24[w][grp * 4] = t4;
        }
    }
    __syncthreads();  // B2

    // ---- w3 (threads 0..127)
    if (tid < C_) {
        float cs = s_cs4[0][tid] + s_cs4[1][tid] + s_cs4[2][tid] + s_cs4[3][tid];
        float w3 = v12 / (EPS_ATT + cs);
        s_w3bf[tid] = bf16b(w3);
    }
    __syncthreads();  // B3

    // ---- MFMA-xr: [S1 | xr_raw] = e . [f1bf | w3bf]  (frags from registers)
    {
        const short8 z8 = {0, 0, 0, 0, 0, 0, 0, 0};
        short8 bq[4];
#pragma unroll
        for (int q = 0; q < 4; ++q) {
            if (ls == 0)
                bq[q] = *(const short8*)&s_f1bf[q * 32 + g * 8];
            else if (ls == 1)
                bq[q] = *(const short8*)&s_w3bf[q * 32 + g * 8];
            else
                bq[q] = z8;
        }
        f32x4 acc0 = {0.f, 0.f, 0.f, 0.f};
        f32x4 acc1 = {0.f, 0.f, 0.f, 0.f};
#pragma unroll
        for (int q = 0; q < 4; ++q) {
            acc0 = __builtin_amdgcn_mfma_f32_16x16x32_bf16(ef0[q], bq[q], acc0, 0, 0, 0);
            acc1 = __builtin_amdgcn_mfma_f32_16x16x32_bf16(ef1[q], bq[q], acc1, 0, 0, 0);
        }
        if (ls < 2) {
            float* dst = ls ? s_xr : s_S1;
            *(f32x4*)&dst[(2 * w + 0) * 16 + g * 4] = acc0;
            *(f32x4*)&dst[(2 * w + 1) * 16 + g * 4] = acc1;
        }
    }
    __syncthreads();  // B4

    // ---- finalize (threads 0..127): gate + out partial; xr normalized in place.
    if (tid < C_) {
        float invz = s_invZ[tid];
        float S1 = s_S1[tid] * invz;
        float xr = s_xr[tid] * invz;
        float S2 = s_s24[0][tid] + s_s24[1][tid] + s_s24[2][tid] + s_s24[3][tid];
        s_xr[tid] = xr;
        float gg = S1 + S2 + s_x1[tid] * fcw[2 * C_] + fcb[0];
        float gate = 1.f / (1.f + __builtin_amdgcn_exp2f(-LOG2E * gg));
        GX1[b * C_ + tid] = gate * s_x1[tid];
    }
    __syncthreads();  // B5

    // ---- conv: t = W.xr via WT, float4 loads. Thread: cols quad*4..+3,
    // rows chunk*16..+15. Partials into s_buf (e-matrix is dead).
    {
        const int quad = tid & 31;
        const int chunk = tid >> 5;
        f32x4 acc = {0.f, 0.f, 0.f, 0.f};
#pragma unroll
        for (int ii = 0; ii < 16; ++ii) {
            const int i = chunk * 16 + ii;
            const float x = s_xr[i];  // broadcast (2 addrs/wave, diff banks)
            f32x4 wv = *(const f32x4*)&WT[i * C_ + quad * 4];
            acc[0] = fmaf(wv[0], x, acc[0]);
            acc[1] = fmaf(wv[1], x, acc[1]);
            acc[2] = fmaf(wv[2], x, acc[2]);
            acc[3] = fmaf(wv[3], x, acc[3]);
        }
        float* tp4 = (float*)s_buf;
        *(f32x4*)&tp4[chunk * C_ + quad * 4] = acc;
    }
    __syncthreads();  // B6

    if (tid < C_) {
        const float* tp4 = (const float*)s_buf;
        float t = vcb;
#pragma unroll
        for (int k = 0; k < 8; ++k) t += tp4[k * C_ + tid];
        Y[b * C_ + tid] = s_x1[tid] - t;
    }
}

// ---------------------------------------------------------------------------
// Kernel 2: coalesced per-channel partial stats. 64 blocks x 64 rows each,
// pure float4 row reads; per-quad tree reduce; partials -> pst[ch*64+slice]
// (sums) and pst[8192+ch*64+slice] (sumsq).
__global__ __launch_bounds__(256) void k_pstat(const float* __restrict__ Y,
                                               float* __restrict__ pst) {
    const int slice = blockIdx.x;  // 0..63
    const int t = threadIdx.x;
    const f32x4* Yb = (const f32x4*)(Y + slice * 64 * C_);
    f32x4 s = {0.f, 0.f, 0.f, 0.f};
    f32x4 q = {0.f, 0.f, 0.f, 0.f};
#pragma unroll
    for (int p = 0; p < 8; ++p) {
        f32x4 y = Yb[p * 256 + t];  // channel quad = t&31, fixed across p
        s += y;
        q += y * y;
    }
    __shared__ f32x4 sh[256];
    __shared__ f32x4 sh2[256];
    sh[t] = s;
    sh2[t] = q;
    __syncthreads();
#pragma unroll
    for (int off = 128; off >= 32; off >>= 1) {
        if (t < off) {
            sh[t] += sh[t + off];
            sh2[t] += sh2[t + off];
        }
        __syncthreads();
    }
    if (t < 32) {
        f32x4 a = sh[t];
        f32x4 b2 = sh2[t];
#pragma unroll
        for (int j = 0; j < 4; ++j) {
            pst[(t * 4 + j) * 64 + slice] = a[j];
            pst[8192 + (t * 4 + j) * 64 + slice] = b2[j];
        }
    }
}

// ---------------------------------------------------------------------------
// Kernel 3: preamble folds the 64 slice-partials into scale/shift (replaces
// the old k_stats dispatch), then out += relu(Y*A + Bc), float4. y/o loads
// issued before the preamble so they overlap the partial reduction.
__global__ __launch_bounds__(256) void k_final(const float* __restrict__ Y,
                                               const float* __restrict__ pst,
                                               const float* __restrict__ gamma,
                                               const float* __restrict__ beta,
                                               float* __restrict__ out) {
    const int t = threadIdx.x;
    const int i4 = blockIdx.x * 256 + t;  // float4 index; grid covers exactly
    float4 y = ((const float4*)Y)[i4];
    float4 o = ((const float4*)out)[i4];
    __shared__ float sA[C_];
    __shared__ float sB[C_];
    if (t < C_) {
        f32x4 a = {0.f, 0.f, 0.f, 0.f};
        f32x4 b2 = {0.f, 0.f, 0.f, 0.f};
#pragma unroll
        for (int k = 0; k < 16; ++k) {
            a += *(const f32x4*)&pst[t * 64 + k * 4];
            b2 += *(const f32x4*)&pst[8192 + t * 64 + k * 4];
        }
        float s = (a[0] + a[1]) + (a[2] + a[3]);
        float q = (b2[0] + b2[1]) + (b2[2] + b2[3]);
        float mean = s * (1.f / (float)B_);
        float var = q * (1.f / (float)B_) - mean * mean;
        float A = gamma[t] * rsqrtf(var + EPS_BN);
        sA[t] = A;
        sB[t] = beta[t] - mean * A;
    }
    __syncthreads();
    const int ch = (i4 * 4) & (C_ - 1);
    o.x += fmaxf(y.x * sA[ch + 0] + sB[ch + 0], 0.f);
    o.y += fmaxf(y.y * sA[ch + 1] + sB[ch + 1], 0.f);
    o.z += fmaxf(y.z * sA[ch + 2] + sB[ch + 2], 0.f);
    o.w += fmaxf(y.w * sA[ch + 3] + sB[ch + 3], 0.f);
    ((float4*)out)[i4] = o;
}

// ---------------------------------------------------------------------------
extern "C" void kernel_launch(void* const* d_in, const int* in_sizes, int n_in,
                              void* d_out, int out_size, void* d_ws,
                              size_t ws_size, hipStream_t stream) {
    const float* x1 = (const float*)d_in[0];
    const float* x2 = (const float*)d_in[1];
    const float* x12 = (const float*)d_in[2];
    const float* convw = (const float*)d_in[3];
    const float* convb = (const float*)d_in[4];
    const float* gamma = (const float*)d_in[5];
    const float* beta = (const float*)d_in[6];
    const float* fcw = (const float*)d_in[7];
    const float* fcb = (const float*)d_in[8];
    float* out = (float*)d_out;

    float* WT = (float*)d_ws;             // C*C
    float* Y = WT + C_ * C_;              // B*C
    float* pst = Y + (size_t)B_ * C_;     // 2*128*64

    k_transpose<<<(C_ * C_ + 255) / 256, 256, 0, stream>>>(convw, WT);
    k_batch<<<B_, 256, 0, stream>>>(x1, x2, x12, WT, fcw, fcb, convb, Y, out);
    k_pstat<<<64, 256, 0, stream>>>(Y, pst);
    k_final<<<(B_ * C_ / 4) / 256, 256, 0, stream>>>(Y, pst, gamma, beta, out);
}

// Round 2
// 40.483 us; speedup vs baseline: 1.2529x; 1.0504x over previous
//
#include <hip/hip_runtime.h>

#define B_ 4096
#define C_ 128
#define EPS_ATT 1e-9f
#define EPS_BN 1e-5f
#define LOG2E 1.44269504088896f

using short8 = __attribute__((ext_vector_type(8))) short;
using f32x4 = __attribute__((ext_vector_type(4))) float;
using u32x2 = __attribute__((ext_vector_type(2))) unsigned int;

__device__ __forceinline__ unsigned short bf16b(float x) {
    __bf16 h = (__bf16)x;
    return __builtin_bit_cast(unsigned short, h);
}

// ---------------------------------------------------------------------------
// Kernel 1: one batch per block, 256 threads (4 waves).
// R2: conv/Y moved OUT (to k_conv). k_batch ends at finalize, writing
// normalized xr to global. S1/xr/w3bf alias the dead e-buffer -> LDS
// 39168B -> 4 blocks/CU (was 3). Two fewer barriers.
__global__ __launch_bounds__(256, 4) void k_batch(
    const float* __restrict__ x1, const float* __restrict__ x2,
    const float* __restrict__ x12,
    const float* __restrict__ fcw, const float* __restrict__ fcb,
    float* __restrict__ XR, float* __restrict__ GX1) {
    const int b = blockIdx.x;
    const int tid = threadIdx.x;
    const int lane = tid & 63;
    const int w = tid >> 6;     // wave 0..3
    const int g = lane >> 4;    // k-group 0..3
    const int ls = lane & 15;   // sixteen-index

    // 32KB: bf16 e[128][128] (swizzled rows) during P1/P2.
    // After B2 e is dead: bytes 0..511 = S1, 512..1023 = xr_raw,
    // 1024..1279 = w3bf.
    __shared__ char s_buf[C_ * C_ * 2] __attribute__((aligned(16)));
    __shared__ float s_x1[C_] __attribute__((aligned(16)));
    __shared__ float s_x2[C_] __attribute__((aligned(16)));
    __shared__ float s_fcC[C_] __attribute__((aligned(16)));
    __shared__ float s_invZ[C_] __attribute__((aligned(16)));
    __shared__ float s_cs4[4][C_] __attribute__((aligned(16)));
    __shared__ float s_s24[4][C_] __attribute__((aligned(16)));
    __shared__ unsigned short s_f1bf[C_] __attribute__((aligned(16)));

    float* s_S1 = (float*)s_buf;
    float* s_xrr = (float*)(s_buf + 512);
    unsigned short* s_w3bf = (unsigned short*)(s_buf + 1024);

    // ---- preload (threads 0..127, coalesced). v12 prefetched to reg.
    float v12 = 0.f;
    if (tid < C_) {
        s_x1[tid] = x1[b * C_ + tid];
        s_x2[tid] = x2[b * C_ + tid];
        s_f1bf[tid] = bf16b(fcw[tid]);
        s_fcC[tid] = fcw[C_ + tid];
        v12 = x12[b * C_ + tid];
    }
    __syncthreads();  // B0

    // ---- P1: e-fragments in registers + bf16 e staged to swizzled LDS.
    // Row r cell c (16B = 8 cols) stored at byte r*256 + ((c ^ (r&7))<<4).
    short8 ef0[4], ef1[4];  // tiles m0=2w, m1=2w+1; chunks q=0..3
    float zp0 = 0.f, zp1 = 0.f;
    {
        const float r0 = s_x1[32 * w + ls] * LOG2E;
        const float r1 = s_x1[32 * w + 16 + ls] * LOG2E;
        char* erow0 = s_buf + (32 * w + ls) * 256;
        char* erow1 = s_buf + (32 * w + 16 + ls) * 256;
        const int sw = (ls & 7) << 4;  // same for both rows (differ by 16)
#pragma unroll
        for (int q = 0; q < 4; ++q) {
            f32x4 xa = *(const f32x4*)&s_x2[32 * q + 8 * g];      // broadcast
            f32x4 xb = *(const f32x4*)&s_x2[32 * q + 8 * g + 4];  // broadcast
            union {
                short8 v;
                unsigned short u[8];
            } p0, p1;
#pragma unroll
            for (int j = 0; j < 4; ++j) {
                float a0 = __builtin_amdgcn_exp2f(r0 * xa[j]);
                float b0 = __builtin_amdgcn_exp2f(r0 * xb[j]);
                float a1 = __builtin_amdgcn_exp2f(r1 * xa[j]);
                float b1 = __builtin_amdgcn_exp2f(r1 * xb[j]);
                zp0 += a0 + b0;
                zp1 += a1 + b1;
                p0.u[j] = bf16b(a0);
                p0.u[j + 4] = bf16b(b0);
                p1.u[j] = bf16b(a1);
                p1.u[j + 4] = bf16b(b1);
            }
            ef0[q] = p0.v;
            ef1[q] = p1.v;
            const int off = (64 * q + 16 * g) ^ sw;  // swizzled cell offset
            *(short8*)(erow0 + off) = p0.v;
            *(short8*)(erow1 + off) = p1.v;
        }
    }
    // butterfly over g-lanes (xor 16, then 32): every lane gets full row sums
    zp0 += __shfl_xor(zp0, 16);
    zp0 += __shfl_xor(zp0, 32);
    zp1 += __shfl_xor(zp1, 16);
    zp1 += __shfl_xor(zp1, 32);
    if (lane < 16) {
        s_invZ[32 * w + ls] = 1.f / zp0;
        s_invZ[32 * w + 16 + ls] = 1.f / zp1;
    }
    __syncthreads();  // B1

    // ---- P2: colsum/S2 from staged bf16 e (no exp recompute).
    {
        const int grp = tid & 31;
        const int sl = tid >> 5;
        const char* eb = s_buf + sl * 16 * 256;
        const int octb = grp >> 1;        // 16B cell index
        const int hoff = (grp & 1) * 8;   // half-cell byte offset
        float cs[4] = {0.f, 0.f, 0.f, 0.f};
        float s2[4] = {0.f, 0.f, 0.f, 0.f};
#pragma unroll
        for (int k = 0; k < 4; ++k) {
            f32x4 iz4 = *(const f32x4*)&s_invZ[sl * 16 + 4 * k];  // broadcast
            f32x4 fc4 = *(const f32x4*)&s_fcC[sl * 16 + 4 * k];   // broadcast
#pragma unroll
            for (int rr = 0; rr < 4; ++rr) {
                const int r = 4 * k + rr;
                const float iz = iz4[rr];
                const float izf = iz * fc4[rr];
                u32x2 ev = *(const u32x2*)(eb + r * 256 +
                                           ((octb ^ (r & 7)) << 4) + hoff);
#pragma unroll
                for (int d = 0; d < 2; ++d) {
                    float elo = __builtin_bit_cast(float, ev[d] << 16);
                    float ehi =
                        __builtin_bit_cast(float, ev[d] & 0xffff0000u);
                    cs[2 * d] = fmaf(elo, iz, cs[2 * d]);
                    s2[2 * d] = fmaf(elo, izf, s2[2 * d]);
                    cs[2 * d + 1] = fmaf(ehi, iz, cs[2 * d + 1]);
                    s2[2 * d + 1] = fmaf(ehi, izf, s2[2 * d + 1]);
                }
            }
        }
#pragma unroll
        for (int k = 0; k < 4; ++k) {
            cs[k] += __shfl_xor(cs[k], 32);
            s2[k] += __shfl_xor(s2[k], 32);
        }
        if ((sl & 1) == 0) {  // lanes 0..31 of each wave
            f32x4 c4 = {cs[0], cs[1], cs[2], cs[3]};
            f32x4 t4 = {s2[0], s2[1], s2[2], s2[3]};
            *(f32x4*)&s_cs4[w][grp * 4] = c4;
            *(f32x4*)&s_s24[w][grp * 4] = t4;
        }
    }
    __syncthreads();  // B2  (e-buffer dead from here)

    // ---- w3 (threads 0..127)
    if (tid < C_) {
        float cs = s_cs4[0][tid] + s_cs4[1][tid] + s_cs4[2][tid] + s_cs4[3][tid];
        float w3 = v12 / (EPS_ATT + cs);
        s_w3bf[tid] = bf16b(w3);
    }
    __syncthreads();  // B3

    // ---- MFMA-xr: [S1 | xr_raw] = e . [f1bf | w3bf]  (frags from registers)
    {
        const short8 z8 = {0, 0, 0, 0, 0, 0, 0, 0};
        short8 bq[4];
#pragma unroll
        for (int q = 0; q < 4; ++q) {
            if (ls == 0)
                bq[q] = *(const short8*)&s_f1bf[q * 32 + g * 8];
            else if (ls == 1)
                bq[q] = *(const short8*)&s_w3bf[q * 32 + g * 8];
            else
                bq[q] = z8;
        }
        f32x4 acc0 = {0.f, 0.f, 0.f, 0.f};
        f32x4 acc1 = {0.f, 0.f, 0.f, 0.f};
#pragma unroll
        for (int q = 0; q < 4; ++q) {
            acc0 = __builtin_amdgcn_mfma_f32_16x16x32_bf16(ef0[q], bq[q], acc0, 0, 0, 0);
            acc1 = __builtin_amdgcn_mfma_f32_16x16x32_bf16(ef1[q], bq[q], acc1, 0, 0, 0);
        }
        if (ls < 2) {
            float* dst = ls ? s_xrr : s_S1;
            *(f32x4*)&dst[(2 * w + 0) * 16 + g * 4] = acc0;
            *(f32x4*)&dst[(2 * w + 1) * 16 + g * 4] = acc1;
        }
    }
    __syncthreads();  // B4

    // ---- finalize (threads 0..127): gate -> GX1; normalized xr -> global.
    if (tid < C_) {
        float invz = s_invZ[tid];
        float S1 = s_S1[tid] * invz;
        float xr = s_xrr[tid] * invz;
        float S2 = s_s24[0][tid] + s_s24[1][tid] + s_s24[2][tid] + s_s24[3][tid];
        XR[b * C_ + tid] = xr;
        float gg = S1 + S2 + s_x1[tid] * fcw[2 * C_] + fcb[0];
        float gate = 1.f / (1.f + __builtin_amdgcn_exp2f(-LOG2E * gg));
        GX1[b * C_ + tid] = gate * s_x1[tid];
    }
}

// ---------------------------------------------------------------------------
// Kernel 2: W-stationary conv + Y + BN partial stats. Grid 256 (1 block/CU),
// 512 threads. W staged transposed+swizzled into LDS ONCE per block
// (W L2 traffic 256MB -> 16MB). Thread = (o-quad q, batch-pair sub, i-half
// ih): 1 ds_read_b128 of W feeds 8 FMA. Fuses y = x1 - (W.xr + b), the Y
// write, and per-block per-channel sum/sumsq partials (absorbs k_pstat).
__global__ __launch_bounds__(512, 2) void k_conv(
    const float* __restrict__ W, const float* __restrict__ XR,
    const float* __restrict__ x1, const float* __restrict__ convb,
    float* __restrict__ Y, float* __restrict__ pst) {
    const int blk = blockIdx.x;  // 0..255
    const int tid = threadIdx.x;
    const int bb = blk * 16;

    __shared__ float s_W[C_ * C_] __attribute__((aligned(16)));   // 64KB
    __shared__ float s_xr[16 * C_] __attribute__((aligned(16)));  // 8KB
    __shared__ float s_tp[2 * 16 * C_] __attribute__((aligned(16)));  // 16KB

    // stage W transposed + swizzled: s_W[i*128 + (o ^ (i&28))] = W[o][i].
    // Quad-aligned XOR keeps b128 reads contiguous; row reads conflict-free.
#pragma unroll
    for (int k = 0; k < 32; ++k) {
        int j = k * 512 + tid;
        int o = j >> 7, i = j & 127;
        s_W[i * C_ + (o ^ (i & 28))] = W[j];
    }
#pragma unroll
    for (int k = 0; k < 4; ++k) {
        int j = k * 512 + tid;
        s_xr[j] = XR[bb * C_ + j];
    }
    __syncthreads();  // B0

    // conv: per thread 2 batches x 4 outputs over one i-half.
    const int q = tid & 31;
    const int sub = (tid >> 5) & 7;
    const int ih = tid >> 8;
    const int bl0 = 2 * sub, bl1 = bl0 + 1;
    {
        f32x4 a0 = {0.f, 0.f, 0.f, 0.f};
        f32x4 a1 = {0.f, 0.f, 0.f, 0.f};
#pragma unroll
        for (int iq = 0; iq < 16; ++iq) {
            const int i0 = ih * 64 + 4 * iq;
            f32x4 xv0 = *(const f32x4*)&s_xr[bl0 * C_ + i0];  // broadcast
            f32x4 xv1 = *(const f32x4*)&s_xr[bl1 * C_ + i0];  // broadcast
#pragma unroll
            for (int u = 0; u < 4; ++u) {
                const int i = i0 + u;
                f32x4 wv = *(const f32x4*)&s_W[i * C_ + ((4 * q) ^ (i & 28))];
                a0[0] = fmaf(wv[0], xv0[u], a0[0]);
                a0[1] = fmaf(wv[1], xv0[u], a0[1]);
                a0[2] = fmaf(wv[2], xv0[u], a0[2]);
                a0[3] = fmaf(wv[3], xv0[u], a0[3]);
                a1[0] = fmaf(wv[0], xv1[u], a1[0]);
                a1[1] = fmaf(wv[1], xv1[u], a1[1]);
                a1[2] = fmaf(wv[2], xv1[u], a1[2]);
                a1[3] = fmaf(wv[3], xv1[u], a1[3]);
            }
        }
        *(f32x4*)&s_tp[(ih * 16 + bl0) * C_ + 4 * q] = a0;
        *(f32x4*)&s_tp[(ih * 16 + bl1) * C_ + 4 * q] = a1;
    }
    __syncthreads();  // B1  (s_W dead)

    // combine halves, y = x1 - t, write Y, stats partials into s_W alias.
    float* s_sa = s_W;            // [16][128] sums
    float* s_sb = s_W + 16 * C_;  // [16][128] sumsq
    {
        const int bl = tid >> 5;  // 0..15
        const int gb = bb + bl;
        f32x4 t4 = *(const f32x4*)&s_tp[bl * C_ + 4 * q];
        f32x4 t4b = *(const f32x4*)&s_tp[(16 + bl) * C_ + 4 * q];
        f32x4 cb = *(const f32x4*)&convb[4 * q];
        f32x4 xv = *(const f32x4*)&x1[gb * C_ + 4 * q];
        f32x4 y;
#pragma unroll
        for (int u = 0; u < 4; ++u) y[u] = xv[u] - (t4[u] + t4b[u] + cb[u]);
        *(f32x4*)&Y[gb * C_ + 4 * q] = y;
        *(f32x4*)&s_sa[bl * C_ + 4 * q] = y;
        f32x4 y2;
#pragma unroll
        for (int u = 0; u < 4; ++u) y2[u] = y[u] * y[u];
        *(f32x4*)&s_sb[bl * C_ + 4 * q] = y2;
    }
    __syncthreads();  // B2

    // reduce 16 batch-rows -> per-channel block partial; write pst slices.
    if (tid < 64) {
        const int qq = tid & 31;
        const float* src = (tid < 32) ? s_sa : s_sb;
        f32x4 acc = {0.f, 0.f, 0.f, 0.f};
#pragma unroll
        for (int bl = 0; bl < 16; ++bl)
            acc += *(const f32x4*)&src[bl * C_ + 4 * qq];
        float* dst = pst + (tid < 32 ? 0 : C_ * 256);
#pragma unroll
        for (int j = 0; j < 4; ++j) dst[(4 * qq + j) * 256 + blk] = acc[j];
    }
}

// ---------------------------------------------------------------------------
// Kernel 3: fold 256 slice-partials into scale/shift (all 16 waves busy via
// 4-segment parallel reduce), then out += relu(Y*A + Bc), float4.
__global__ __launch_bounds__(1024) void k_final(const float* __restrict__ Y,
                                                const float* __restrict__ pst,
                                                const float* __restrict__ gamma,
                                                const float* __restrict__ beta,
                                                float* __restrict__ out) {
    const int t = threadIdx.x;
    const int i4 = blockIdx.x * 1024 + t;  // float4 index; grid covers exactly
    float4 y = ((const float4*)Y)[i4];
    float4 o = ((const float4*)out)[i4];

    __shared__ float s_red[2][4][C_];
    __shared__ float sA[C_];
    __shared__ float sB[C_];
    {   // all 1024 threads: (arr, seg, ch) each sums 64 partials
        const int ch = t & 127;
        const int seg = (t >> 7) & 3;
        const int arr = t >> 9;
        const float* src = pst + arr * (C_ * 256) + ch * 256 + seg * 64;
        f32x4 a = {0.f, 0.f, 0.f, 0.f};
#pragma unroll
        for (int k = 0; k < 16; ++k) a += *(const f32x4*)&src[4 * k];
        s_red[arr][seg][ch] = (a[0] + a[1]) + (a[2] + a[3]);
    }
    __syncthreads();
    if (t < C_) {
        float s = s_red[0][0][t] + s_red[0][1][t] + s_red[0][2][t] + s_red[0][3][t];
        float qv = s_red[1][0][t] + s_red[1][1][t] + s_red[1][2][t] + s_red[1][3][t];
        float mean = s * (1.f / (float)B_);
        float var = qv * (1.f / (float)B_) - mean * mean;
        float A = gamma[t] * rsqrtf(var + EPS_BN);
        sA[t] = A;
        sB[t] = beta[t] - mean * A;
    }
    __syncthreads();
    const int ch = (4 * t) & (C_ - 1);
    o.x += fmaxf(y.x * sA[ch + 0] + sB[ch + 0], 0.f);
    o.y += fmaxf(y.y * sA[ch + 1] + sB[ch + 1], 0.f);
    o.z += fmaxf(y.z * sA[ch + 2] + sB[ch + 2], 0.f);
    o.w += fmaxf(y.w * sA[ch + 3] + sB[ch + 3], 0.f);
    ((float4*)out)[i4] = o;
}

// ---------------------------------------------------------------------------
extern "C" void kernel_launch(void* const* d_in, const int* in_sizes, int n_in,
                              void* d_out, int out_size, void* d_ws,
                              size_t ws_size, hipStream_t stream) {
    const float* x1 = (const float*)d_in[0];
    const float* x2 = (const float*)d_in[1];
    const float* x12 = (const float*)d_in[2];
    const float* convw = (const float*)d_in[3];
    const float* convb = (const float*)d_in[4];
    const float* gamma = (const float*)d_in[5];
    const float* beta = (const float*)d_in[6];
    const float* fcw = (const float*)d_in[7];
    const float* fcb = (const float*)d_in[8];
    float* out = (float*)d_out;

    float* XR = (float*)d_ws;               // B*C
    float* Y = XR + (size_t)B_ * C_;        // B*C
    float* pst = Y + (size_t)B_ * C_;       // 2*C*256

    k_batch<<<B_, 256, 0, stream>>>(x1, x2, x12, fcw, fcb, XR, out);
    k_conv<<<256, 512, 0, stream>>>(convw, XR, x1, convb, Y, pst);
    k_final<<<(B_ * C_ / 4) / 1024, 1024, 0, stream>>>(Y, pst, gamma, beta, out);
}